// Round 16
// baseline (4281.780 us; speedup 1.0000x reference)
//
#include <hip/hip_runtime.h>
#include <hip/hip_bf16.h>
#include <stdint.h>
#include <stddef.h>

#define SEQ   512
#define BATCH 64
#define NIN   1024
#define NHID  1024
#define NG    4096   // 4*NHID

typedef __attribute__((ext_vector_type(8))) short bf16x8;
typedef __attribute__((ext_vector_type(4))) float f32x4;
typedef __attribute__((ext_vector_type(4))) uint32_t u32x4;

static __device__ __forceinline__ ushort f2bf(float f) {
  uint32_t u = __builtin_bit_cast(uint32_t, f);
  uint32_t lsb = (u >> 16) & 1u;
  u += 0x7fffu + lsb;           // round-to-nearest-even
  return (ushort)(u >> 16);
}
static __device__ __forceinline__ ushort f2h(float f) {
  _Float16 h = (_Float16)f;
  return __builtin_bit_cast(ushort, h);
}
static __device__ __forceinline__ float h2f(ushort u) {
  return (float)__builtin_bit_cast(_Float16, u);
}

static __device__ __forceinline__ f32x4 mfma_bf16(bf16x8 a, bf16x8 b, f32x4 c) {
  return __builtin_amdgcn_mfma_f32_16x16x32_bf16(a, b, c, 0, 0, 0);
}

static __device__ __forceinline__ void lds_load16(const ushort* g, ushort* l) {
  __builtin_amdgcn_global_load_lds(
      (const __attribute__((address_space(1))) void*)g,
      (__attribute__((address_space(3))) void*)l, 16, 0, 0);
}

// ---- exchange primitives: DEVICE scope (sc1) -- proven correct r10-r15 ----
static __device__ __forceinline__ void st_short_dev(ushort* p, uint32_t v) {
  asm volatile("global_store_short %0, %1, off sc1" :: "v"(p), "v"(v) : "memory");
}
static __device__ __forceinline__ void st_dword_dev(uint32_t* p, uint32_t v) {
  asm volatile("global_store_dword %0, %1, off sc1" :: "v"(p), "v"(v) : "memory");
}
static __device__ __forceinline__ void st_x4_dev(ushort* p, u32x4 v) {
  asm volatile("global_store_dwordx4 %0, %1, off sc1" :: "v"(p), "v"(v) : "memory");
}
static __device__ __forceinline__ uint32_t ld_dword_dev(const uint32_t* p) {
  uint32_t v;
  asm volatile("global_load_dword %0, %1, off sc1" : "=v"(v) : "v"(p) : "memory");
  return v;
}
static __device__ __forceinline__ u32x4 ld_x4_dev(const ushort* p) {
  u32x4 v;
  asm volatile("global_load_dwordx4 %0, %1, off sc1" : "=v"(v) : "v"(p) : "memory");
  return v;
}
// L1-bypass load (reads own-XCD L2; CDNA L1 is a read cache -> stale-line
// hazard for buffers rewritten by same-block waves; sc0 sidesteps it)
static __device__ __forceinline__ uint32_t ld_ushort_l2(const ushort* p) {
  uint32_t v;
  asm volatile("global_load_ushort %0, %1, off sc0" : "=v"(v) : "v"(p) : "memory");
  return v;
}

#define WAITV(n) do { asm volatile("s_waitcnt vmcnt(" #n ")" ::: "memory"); \
                      __builtin_amdgcn_sched_barrier(0); } while (0)

// fast transcendentals
static __device__ __forceinline__ float sigm_f(float x) {
  return __builtin_amdgcn_rcpf(1.f + __expf(-x));
}
static __device__ __forceinline__ float tanh_f(float x) {
  return 1.f - 2.f * __builtin_amdgcn_rcpf(__expf(2.f * x) + 1.f);
}

// ---------------- converts ----------------

__global__ __launch_bounds__(256) void k_convert_x(const float* __restrict__ X,
                                                   ushort* __restrict__ Xb, int n4) {
  int i = blockIdx.x * 256 + threadIdx.x;
  if (i < n4) {
    float4 v = ((const float4*)X)[i];
    ushort4 o;
    o.x = f2bf(v.x); o.y = f2bf(v.y); o.z = f2bf(v.z); o.w = f2bf(v.w);
    ((ushort4*)Xb)[i] = o;
  }
}

// permuted row order: p = cg*64 + g*16 + j  <->  r = g*1024 + cg*16 + j
__global__ __launch_bounds__(256) void k_convert_w(const float* __restrict__ W,
                                                   const float* __restrict__ bvec,
                                                   ushort* __restrict__ Wxb,
                                                   ushort* __restrict__ Whb,
                                                   float* __restrict__ bp) {
  int p = blockIdx.x;
  int cg = p >> 6, g = (p >> 4) & 3, j = p & 15;
  int r = g * 1024 + cg * 16 + j;
  const float* src = W + (size_t)r * 2048;
  for (int k4 = threadIdx.x; k4 < 512; k4 += 256) {
    float4 v = ((const float4*)src)[k4];
    ushort4 o;
    o.x = f2bf(v.x); o.y = f2bf(v.y); o.z = f2bf(v.z); o.w = f2bf(v.w);
    if (k4 < 256) ((ushort4*)(Wxb + (size_t)p * 1024))[k4] = o;
    else          ((ushort4*)(Whb + (size_t)p * 1024))[k4 - 256] = o;
  }
  if (threadIdx.x == 0) bp[p] = bvec[r];
}

// zero h ping-pong, c-state, replicated flags (16384 dwords)
__global__ __launch_bounds__(256) void k_zero(ushort* __restrict__ hb0,
                                              ushort* __restrict__ hb1,
                                              float* __restrict__ cst,
                                              uint32_t* __restrict__ flg2) {
  int i = blockIdx.x * 256 + threadIdx.x;  // 65536 total
  st_short_dev(hb0 + i, 0u);
  st_short_dev(hb1 + i, 0u);
  cst[i] = 0.f;
  if (i < 256 * 64) st_dword_dev(flg2 + i, 0u);
}

// ---------------- GEMM1: chunk-0 prologue, Ax (f16) = Xb @ Wxb^T + bp ----------------

__global__ __launch_bounds__(256) void k_gemm1(const ushort* __restrict__ Xbc,
                                               const ushort* __restrict__ Wxb,
                                               const float* __restrict__ bp,
                                               ushort* __restrict__ Axc) {
  __shared__ ushort As[128 * 32];
  __shared__ ushort Bs[128 * 32];
  const int m0 = blockIdx.x * 128;
  const int n0 = blockIdx.y * 128;
  const int tid = threadIdx.x;
  const int w = tid >> 6, l = tid & 63;
  const int wr = w >> 1, wc = w & 1;
  const int lr = l >> 2;
  const int lc = (l & 3) * 8;
  const int fr = l & 15, fk8 = (l >> 4) * 8, fq = l >> 4;

  f32x4 acc[4][4] = {};

  for (int kb = 0; kb < 1024; kb += 32) {
    lds_load16(Xbc + (size_t)(m0 + w * 16 + lr) * 1024 + kb + lc,       &As[w * 512]);
    lds_load16(Xbc + (size_t)(m0 + (w + 4) * 16 + lr) * 1024 + kb + lc, &As[(w + 4) * 512]);
    lds_load16(Wxb + (size_t)(n0 + w * 16 + lr) * 1024 + kb + lc,       &Bs[w * 512]);
    lds_load16(Wxb + (size_t)(n0 + (w + 4) * 16 + lr) * 1024 + kb + lc, &Bs[(w + 4) * 512]);
    __syncthreads();
    bf16x8 af[4], bfr[4];
#pragma unroll
    for (int i = 0; i < 4; i++) af[i]  = *(const bf16x8*)&As[(wr * 64 + i * 16 + fr) * 32 + fk8];
#pragma unroll
    for (int i = 0; i < 4; i++) bfr[i] = *(const bf16x8*)&Bs[(wc * 64 + i * 16 + fr) * 32 + fk8];
#pragma unroll
    for (int i = 0; i < 4; i++)
#pragma unroll
      for (int jj = 0; jj < 4; jj++)
        acc[i][jj] = mfma_bf16(af[i], bfr[jj], acc[i][jj]);
    __syncthreads();
  }

#pragma unroll
  for (int jj = 0; jj < 4; jj++) {
    int gc = n0 + wc * 64 + jj * 16 + fr;
    float bb = bp[gc];
#pragma unroll
    for (int i = 0; i < 4; i++) {
      int grb = m0 + wr * 64 + i * 16 + fq * 4;
#pragma unroll
      for (int jr = 0; jr < 4; jr++)
        Axc[(size_t)(grb + jr) * NG + gc] = f2h(acc[i][jj][jr] + bb);
    }
  }
}

// ---------------- fused persistent LSTM with background-GEMM waves ----------------
// 256 blocks x 384 threads (6 waves). Waves 0-3: the r15-champion recurrence
// (unchanged: fan-in-16 sc1 flag poll, counted-vmcnt h pipeline, fragment-
// major Wlds, packed publish, 8-step out batching). Waves 4-5: BACKGROUND
// x-GEMM -- during chunk c (64 steps) they produce THIS BLOCK'S Ax slice for
// chunk c+1 (block-local: rows = team's 16 batches, cols = hg's 64 gate cols,
// one step-row-group per loop iteration = 64 MFMA/wave, ~0.3us of work in the
// 3.67us stall window). Double-buffered Ax chunks (2 x 32MB). Barrier-matched:
// all 6 waves hit both per-step __syncthreads. r14's failure (x-GEMM on the
// reduce critical path) is avoided: production is 64 steps ahead, consumption
// never waits. Ax prefetch uses sc0 loads (L1 is a read cache; lines rewritten
// by same-block gemm waves could be stale in L1; L2 is coherent intra-CU).

__global__ __launch_bounds__(384) void k_persist(const ushort* __restrict__ Whb,
                                                 const ushort* __restrict__ Wxb,
                                                 const ushort* __restrict__ Xb,
                                                 const float* __restrict__ bp,
                                                 ushort* __restrict__ ax0,
                                                 ushort* __restrict__ ax1,
                                                 ushort* __restrict__ hb0,
                                                 ushort* __restrict__ hb1,
                                                 float* __restrict__ out,
                                                 uint32_t* __restrict__ flg2,
                                                 float* __restrict__ cst) {
  __shared__ ushort Wlds[8192 * 8];     // 128 KB fragment-major
  __shared__ float red[4][16][65];      // K-split reduce
  __shared__ ushort h_sh[16][16];       // packed publish tile
  __shared__ float houtlds[8][256];     // 8-step out staging

  const int bid = blockIdx.x;
  const int team = bid >> 6, hg = bid & 63;
  const int tid = threadIdx.x, w = tid >> 6, l = tid & 63;
  const int fr = l & 15, fq = l >> 4;

  // ---- stage Wh slice fragment-major: f = ((kc*4)+bj)*64 + lane ----
  for (int it = tid; it < 8192; it += 384) {
    int fl = it & 63, bj = (it >> 6) & 3, kc = it >> 8;
    bf16x8 v = *(const bf16x8*)(Whb + (size_t)(hg * 64 + bj * 16 + (fl & 15)) * 1024
                                + kc * 32 + (fl >> 4) * 8);
    *(bf16x8*)&Wlds[(size_t)it * 8] = v;
  }
  __syncthreads();

  const int eb = tid >> 4, ej = tid & 15;  // valid for w<4 only
  const int hidx_self = (team * 16 + (eb & 15)) * 1024 + hg * 16 + ej;
  float creg = (w < 4) ? cst[hidx_self] : 0.f;

  const size_t roff = (size_t)(team * 16 + fr) * 1024 + w * 256 + fq * 8;
  const uint32_t* fladdr = flg2 + bid * 64 + w * 16 + (l & 15);  // w<4 only

  // background-gemm constants (w>=4)
  const int wg = w - 4;  // 0 or 1
  const float bb0 = bp[hg * 64 + (wg & 1) * 32 + fr];
  const float bb1 = bp[hg * 64 + (wg & 1) * 32 + 16 + fr];

  for (int tt = 0; tt < SEQ; ++tt) {
    const int c = tt >> 6, tl = tt & 63;
    const ushort* Axc = (c & 1) ? ax1 : ax0;
    ushort*       Axn = (c & 1) ? ax0 : ax1;
    const ushort* hb_r = (tt & 1) ? hb0 : hb1;
    ushort*       hb_w = (tt & 1) ? hb1 : hb0;

    if (w < 4) {
      // ---- Ax prefetch (f16, sc0; overlaps poll) ----
      const ushort* axp = Axc + ((size_t)tl * 64 + team * 16 + eb) * NG + hg * 64;
      ushort axu0 = (ushort)ld_ushort_l2(axp + ej);
      ushort axu1 = (ushort)ld_ushort_l2(axp + 16 + ej);
      ushort axu2 = (ushort)ld_ushort_l2(axp + 32 + ej);
      ushort axu3 = (ushort)ld_ushort_l2(axp + 48 + ej);

      // ---- per-wave 2-deep pipelined poll of 16 producer flags ----
      if (tt > 0) {
        int guard = 0;
        while (true) {
          uint32_t v0 = ld_dword_dev(fladdr);
          uint32_t v1 = ld_dword_dev(fladdr);
          asm volatile("s_waitcnt vmcnt(1)" ::: "memory");
          __builtin_amdgcn_sched_barrier(0);
          bool ok0 = __all((int)(v0 >= (uint32_t)tt));
          asm volatile("s_waitcnt vmcnt(0)" ::: "memory");
          __builtin_amdgcn_sched_barrier(0);
          if (ok0) break;
          if (__all((int)(v1 >= (uint32_t)tt))) break;
          if (++guard > (1 << 15)) break;   // bug guard
        }
      }

      // ---- bulk read h_{t-1} + counted-vmcnt per-slice MFMA pipeline ----
      const ushort* aBt = hb_r + roff;
      u32x4 hv[8];
      f32x4 acc[4] = {};
#pragma unroll
      for (int ks = 0; ks < 8; ++ks) hv[ks] = ld_x4_dev(aBt + ks * 32);
#define SLICE(ks) do {                                                        \
      bf16x8 a_ = __builtin_bit_cast(bf16x8, hv[ks]);                         \
      _Pragma("unroll")                                                       \
      for (int bj = 0; bj < 4; ++bj) {                                        \
        bf16x8 b_ = *(const bf16x8*)&Wlds[(size_t)(((w * 8 + (ks)) * 4 + bj) * 64 + l) * 8]; \
        acc[bj] = mfma_bf16(a_, b_, acc[bj]);                                 \
      }                                                                       \
    } while (0)
      WAITV(7); SLICE(0);
      WAITV(6); SLICE(1);
      WAITV(5); SLICE(2);
      WAITV(4); SLICE(3);
      WAITV(3); SLICE(4);
      WAITV(2); SLICE(5);
      WAITV(1); SLICE(6);
      WAITV(0); SLICE(7);
#undef SLICE

#pragma unroll
      for (int bj = 0; bj < 4; ++bj)
#pragma unroll
        for (int jr = 0; jr < 4; ++jr)
          red[w][fq * 4 + jr][bj * 16 + fr] = acc[bj][jr];

      // stash ax for epilogue via regs (reuse acc slots is fine; recompute not)
      // carry via LDS-free path: store into houtlds? simpler: recompute below
      // -> instead keep in registers across the barrier:
      red[w][fq * 4][64] = 0.f;  // keep array shape used; no-op slot
      // (axu0..3 stay live in registers across __syncthreads)
      __syncthreads();

      // ---- epilogue: one (batch, hcol) per thread ----
      float ai_ = h2f(axu0), af_ = h2f(axu1), ao_ = h2f(axu2), ag_ = h2f(axu3);
#pragma unroll
      for (int ww = 0; ww < 4; ++ww) {
        ai_ += red[ww][eb][ej];
        af_ += red[ww][eb][16 + ej];
        ao_ += red[ww][eb][32 + ej];
        ag_ += red[ww][eb][48 + ej];
      }

      float ig = sigm_f(ai_);
      float fg = sigm_f(af_);
      float og = sigm_f(ao_);
      float gg = tanh_f(ag_);
      creg = creg * fg + ig * gg;
      float h = og * tanh_f(creg);
      h_sh[eb][ej] = f2bf(h);
      houtlds[tt & 7][tid] = h;
      __syncthreads();

      // ---- publish (wave0 only): 32 x 16B h stores -> drain -> 64 flags ----
      if (w == 0) {
        if (l < 32) {
          int prow = l >> 1, phalf = (l & 1) * 8;
          u32x4 pv = *(const u32x4*)&h_sh[prow][phalf];
          st_x4_dev(hb_w + (size_t)(team * 16 + prow) * 1024 + hg * 16 + phalf, pv);
        }
        asm volatile("s_waitcnt vmcnt(0)" ::: "memory");
        __builtin_amdgcn_sched_barrier(0);
        st_dword_dev(flg2 + (team * 64 + l) * 64 + hg, (uint32_t)(tt + 1));
      }

      // ---- flush out (HBM) every 8 steps, strictly after flags ----
      if ((tt & 7) == 7) {
        int tb = tt - 7;
#pragma unroll
        for (int s = 0; s < 8; ++s)
          out[(size_t)(tb + s) * 65536 + hidx_self] = houtlds[s][tid];
      }
      if (tt == SEQ - 1) out[(size_t)SEQ * 65536 + hidx_self] = h;

    } else {
      // ======== background-GEMM waves (w=4,5): produce chunk c+1 ========
      if (c + 1 < 8) {
        int sg = (c + 1) * 64 + tl;   // global step being produced
        const ushort* ax_ = Xb + ((size_t)sg * 64 + team * 16 + fr) * 1024 + fq * 8;
        const ushort* bx_ = Wxb + (size_t)(hg * 64 + wg * 32 + fr) * 1024 + fq * 8;
        f32x4 g0 = {}, g1 = {};
#pragma unroll 4
        for (int ks = 0; ks < 32; ++ks) {
          bf16x8 a_ = *(const bf16x8*)(ax_ + ks * 32);
          bf16x8 b0 = *(const bf16x8*)(bx_ + ks * 32);
          bf16x8 b1 = *(const bf16x8*)(bx_ + (size_t)16 * 1024 + ks * 32);
          g0 = mfma_bf16(a_, b0, g0);
          g1 = mfma_bf16(a_, b1, g1);
        }
        // C layout: col = fr, row = fq*4 + jr (batch-in-team)
#pragma unroll
        for (int jr = 0; jr < 4; ++jr) {
          ushort* axo = Axn + ((size_t)tl * 64 + team * 16 + fq * 4 + jr) * NG
                        + hg * 64 + wg * 32 + fr;
          axo[0]  = f2h(g0[jr] + bb0);
          axo[16] = f2h(g1[jr] + bb1);
        }
        asm volatile("s_waitcnt vmcnt(0)" ::: "memory");  // in L2 before use
      }
      __syncthreads();   // barrier A (matches recurrence)
      __syncthreads();   // barrier B
    }
  }

  if (w < 4) cst[hidx_self] = creg;
}

// ---------------- fallback per-step kernel (ws too small) ----------------

__global__ __launch_bounds__(256) void k_step(int t,
                                              const ushort* __restrict__ Xb,
                                              const ushort* __restrict__ Wxb,
                                              const ushort* __restrict__ Whb,
                                              const float* __restrict__ bp,
                                              const ushort* __restrict__ hprev,
                                              ushort* __restrict__ hnext,
                                              float* __restrict__ cst,
                                              float* __restrict__ out) {
  __shared__ float red[4][16][65];
  const int bidx = blockIdx.x;
  const int cg = bidx & 63, mb = bidx >> 6;
  const int b0 = mb * 16, pcol = cg * 64;
  const int tid = threadIdx.x, w = tid >> 6, l = tid & 63;
  const int fr = l & 15, fk8 = (l >> 4) * 8, fq = l >> 4;

  f32x4 acc[4] = {};

  const ushort* aSrc;
  const ushort* bMat;
  int kbase;
  if (w < 2) { aSrc = Xb + (size_t)(t * 64 + b0 + fr) * 1024 + w * 512 + fk8; bMat = Wxb; kbase = w * 512; }
  else       { aSrc = hprev + (size_t)(b0 + fr) * 1024 + (w - 2) * 512 + fk8; bMat = Whb; kbase = (w - 2) * 512; }
  const ushort* bRow = bMat + (size_t)(pcol + fr) * 1024 + kbase + fk8;

#pragma unroll
  for (int ks = 0; ks < 16; ks++) {
    int kk = ks * 32;
    bf16x8 a = *(const bf16x8*)(aSrc + kk);
#pragma unroll
    for (int bj = 0; bj < 4; bj++) {
      bf16x8 bfv = *(const bf16x8*)(bRow + (size_t)bj * 16 * 1024 + kk);
      acc[bj] = mfma_bf16(a, bfv, acc[bj]);
    }
  }

#pragma unroll
  for (int bj = 0; bj < 4; bj++)
#pragma unroll
    for (int jr = 0; jr < 4; jr++)
      red[w][fq * 4 + jr][bj * 16 + fr] = acc[bj][jr];
  __syncthreads();

  const int b = tid >> 4, j = tid & 15;
  float ai_ = 0.f, af_ = 0.f, ao_ = 0.f, ag_ = 0.f;
#pragma unroll
  for (int ww = 0; ww < 4; ww++) {
    ai_ += red[ww][b][j];
    af_ += red[ww][b][16 + j];
    ao_ += red[ww][b][32 + j];
    ag_ += red[ww][b][48 + j];
  }
  ai_ += bp[pcol + j]; af_ += bp[pcol + 16 + j]; ao_ += bp[pcol + 32 + j]; ag_ += bp[pcol + 48 + j];

  float ig = sigm_f(ai_);
  float fg = sigm_f(af_);
  float og = sigm_f(ao_);
  float gg = tanh_f(ag_);
  int hidx = (b0 + b) * 1024 + cg * 16 + j;
  float cn = cst[hidx] * fg + ig * gg;
  cst[hidx] = cn;
  float h = og * tanh_f(cn);
  out[(size_t)t * 65536 + hidx] = h;
  hnext[hidx] = f2bf(h);
  if (t == SEQ - 1) out[(size_t)SEQ * 65536 + hidx] = h;
}

// ---------------- host ----------------

extern "C" void kernel_launch(void* const* d_in, const int* in_sizes, int n_in,
                              void* d_out, int out_size, void* d_ws, size_t ws_size,
                              hipStream_t stream) {
  const float* X    = (const float*)d_in[0];
  const float* W    = (const float*)d_in[1];
  const float* bvec = (const float*)d_in[2];
  float* out = (float*)d_out;
  char* ws = (char*)d_ws;

  size_t off = 0;
  auto alloc = [&](size_t bytes) -> char* {
    char* p = ws + off;
    off += (bytes + 255) & ~(size_t)255;
    return p;
  };
  ushort*   Xb   = (ushort*)alloc((size_t)SEQ * BATCH * NIN * 2);
  ushort*   Wxb  = (ushort*)alloc((size_t)NG * NIN * 2);
  ushort*   Whb  = (ushort*)alloc((size_t)NG * NHID * 2);
  float*    bp   = (float*)alloc((size_t)NG * 4);
  ushort*   hb0  = (ushort*)alloc((size_t)BATCH * NHID * 2);
  ushort*   hb1  = (ushort*)alloc((size_t)BATCH * NHID * 2);
  float*    cst  = (float*)alloc((size_t)BATCH * NHID * 4);
  uint32_t* flg2 = (uint32_t*)alloc(256 * 64 * 4);   // replicated flags
  size_t base_need = off;
  ushort*   ax0  = (ushort*)alloc((size_t)64 * BATCH * NG * 2);  // 32 MB
  ushort*   ax1  = (ushort*)alloc((size_t)64 * BATCH * NG * 2);  // 32 MB
  size_t fused_need = off;

  if (ws_size < base_need) return;
  const bool fused = (ws_size >= fused_need);

  k_convert_x<<<(SEQ * BATCH * NIN / 4 + 255) / 256, 256, 0, stream>>>(X, Xb, SEQ * BATCH * NIN / 4);
  k_convert_w<<<NG, 256, 0, stream>>>(W, bvec, Wxb, Whb, bp);
  k_zero<<<BATCH * NHID / 256, 256, 0, stream>>>(hb0, hb1, cst, flg2);

  if (fused) {
    // prologue: chunk 0 (steps 0-63, M = 4096 rows) into ax0
    k_gemm1<<<dim3(32, 32), 256, 0, stream>>>(Xb, Wxb, bp, ax0);
    k_persist<<<256, 384, 0, stream>>>(Whb, Wxb, Xb, bp, ax0, ax1,
                                       hb0, hb1, out, flg2, cst);
  } else {
    for (int t = 0; t < SEQ; t++) {
      const ushort* hp = (t & 1) ? hb1 : hb0;
      ushort*       hn = (t & 1) ? hb0 : hb1;
      k_step<<<256, 256, 0, stream>>>(t, Xb, Wxb, Whb, bp, hp, hn, cst, out);
    }
  }
}

// Round 17
// 2223.403 us; speedup vs baseline: 1.9258x; 1.9258x over previous
//
#include <hip/hip_runtime.h>
#include <hip/hip_bf16.h>
#include <stdint.h>
#include <stddef.h>

#define SEQ   512
#define BATCH 64
#define NIN   1024
#define NHID  1024
#define NG    4096   // 4*NHID

typedef __attribute__((ext_vector_type(8))) short bf16x8;
typedef __attribute__((ext_vector_type(4))) float f32x4;
typedef __attribute__((ext_vector_type(4))) uint32_t u32x4;

static __device__ __forceinline__ ushort f2bf(float f) {
  uint32_t u = __builtin_bit_cast(uint32_t, f);
  uint32_t lsb = (u >> 16) & 1u;
  u += 0x7fffu + lsb;           // round-to-nearest-even
  return (ushort)(u >> 16);
}
static __device__ __forceinline__ ushort f2h(float f) {
  _Float16 h = (_Float16)f;
  return __builtin_bit_cast(ushort, h);
}
static __device__ __forceinline__ float h2f(ushort u) {
  return (float)__builtin_bit_cast(_Float16, u);
}

static __device__ __forceinline__ f32x4 mfma_bf16(bf16x8 a, bf16x8 b, f32x4 c) {
  return __builtin_amdgcn_mfma_f32_16x16x32_bf16(a, b, c, 0, 0, 0);
}

static __device__ __forceinline__ void lds_load16(const ushort* g, ushort* l) {
  __builtin_amdgcn_global_load_lds(
      (const __attribute__((address_space(1))) void*)g,
      (__attribute__((address_space(3))) void*)l, 16, 0, 0);
}

// ---- exchange primitives: DEVICE scope (sc1) -- proven correct r10-r15 ----
static __device__ __forceinline__ void st_short_dev(ushort* p, uint32_t v) {
  asm volatile("global_store_short %0, %1, off sc1" :: "v"(p), "v"(v) : "memory");
}
static __device__ __forceinline__ void st_dword_dev(uint32_t* p, uint32_t v) {
  asm volatile("global_store_dword %0, %1, off sc1" :: "v"(p), "v"(v) : "memory");
}
static __device__ __forceinline__ void st_x4_dev(ushort* p, u32x4 v) {
  asm volatile("global_store_dwordx4 %0, %1, off sc1" :: "v"(p), "v"(v) : "memory");
}
static __device__ __forceinline__ uint32_t ld_dword_dev(const uint32_t* p) {
  uint32_t v;
  asm volatile("global_load_dword %0, %1, off sc1" : "=v"(v) : "v"(p) : "memory");
  return v;
}
static __device__ __forceinline__ u32x4 ld_x4_dev(const ushort* p) {
  u32x4 v;
  asm volatile("global_load_dwordx4 %0, %1, off sc1" : "=v"(v) : "v"(p) : "memory");
  return v;
}

#define WAITV(n) do { asm volatile("s_waitcnt vmcnt(" #n ")" ::: "memory"); \
                      __builtin_amdgcn_sched_barrier(0); } while (0)

// fast transcendentals
static __device__ __forceinline__ float sigm_f(float x) {
  return __builtin_amdgcn_rcpf(1.f + __expf(-x));
}
static __device__ __forceinline__ float tanh_f(float x) {
  return 1.f - 2.f * __builtin_amdgcn_rcpf(__expf(2.f * x) + 1.f);
}

// ---------------- converts ----------------

__global__ __launch_bounds__(256) void k_convert_x(const float* __restrict__ X,
                                                   ushort* __restrict__ Xb, int n4) {
  int i = blockIdx.x * 256 + threadIdx.x;
  if (i < n4) {
    float4 v = ((const float4*)X)[i];
    ushort4 o;
    o.x = f2bf(v.x); o.y = f2bf(v.y); o.z = f2bf(v.z); o.w = f2bf(v.w);
    ((ushort4*)Xb)[i] = o;
  }
}

// permuted row order: p = cg*64 + g*16 + j  <->  r = g*1024 + cg*16 + j
__global__ __launch_bounds__(256) void k_convert_w(const float* __restrict__ W,
                                                   const float* __restrict__ bvec,
                                                   ushort* __restrict__ Wxb,
                                                   ushort* __restrict__ Whb,
                                                   float* __restrict__ bp) {
  int p = blockIdx.x;
  int cg = p >> 6, g = (p >> 4) & 3, j = p & 15;
  int r = g * 1024 + cg * 16 + j;
  const float* src = W + (size_t)r * 2048;
  for (int k4 = threadIdx.x; k4 < 512; k4 += 256) {
    float4 v = ((const float4*)src)[k4];
    ushort4 o;
    o.x = f2bf(v.x); o.y = f2bf(v.y); o.z = f2bf(v.z); o.w = f2bf(v.w);
    if (k4 < 256) ((ushort4*)(Wxb + (size_t)p * 1024))[k4] = o;
    else          ((ushort4*)(Whb + (size_t)p * 1024))[k4 - 256] = o;
  }
  if (threadIdx.x == 0) bp[p] = bvec[r];
}

// zero h ping-pong, c-state, replicated flags (16384 dwords)
__global__ __launch_bounds__(256) void k_zero(ushort* __restrict__ hb0,
                                              ushort* __restrict__ hb1,
                                              float* __restrict__ cst,
                                              uint32_t* __restrict__ flg2) {
  int i = blockIdx.x * 256 + threadIdx.x;  // 65536 total
  st_short_dev(hb0 + i, 0u);
  st_short_dev(hb1 + i, 0u);
  cst[i] = 0.f;
  if (i < 256 * 64) st_dword_dev(flg2 + i, 0u);
}

// ---------------- 8-phase 256x256 GEMM: Axc (f16) = Xb @ Wxb^T + bp ----------------
// BM=BN=256, BK=64, 512 threads (8 waves 2Mx4N), 2-buffer LDS (128KB).
// T2: XOR swizzle elem^=(row&7)<<3, applied as linear LDS dest + pre-swizzled
// per-lane GLOBAL source for global_load_lds (rule #21), same XOR on ds_read.
// T3+T4: 4 staging phases/K-tile, one half-tile (2 gload_lds/thread) each;
// counted vmcnt(4) gate per iter (never 0 until the last tile).
// Region safety (phases (0,0),(0,1),(1,0),(1,1)): Ah0 last read ph1 -> stage
// Ah0(j+2) at ph2; Bh0 last read ph2 -> stage at ph3; Bh1(j+1)/Ah1(j+1)
// staged at ph0/ph1 into the OTHER buffer. T5: setprio around MFMA cluster.

#define G8_PHASE(MS, NS, STAGE) do {                                          \
    __syncthreads();                                                          \
    STAGE;                                                                    \
    bf16x8 aF[4][2], bF[2][2];                                                \
    _Pragma("unroll") for (int mf = 0; mf < 4; ++mf) {                        \
      int R = wr * 128 + (MS) * 64 + mf * 16 + fr;                            \
      _Pragma("unroll") for (int kk = 0; kk < 2; ++kk)                        \
        aF[mf][kk] = *(const bf16x8*)&lds[bufc * 32768 + R * 64 +             \
                       ((kk * 32 + fq * 8) ^ ((fr & 7) << 3))];               \
    }                                                                         \
    _Pragma("unroll") for (int nf = 0; nf < 2; ++nf) {                        \
      int R = wc * 64 + (NS) * 32 + nf * 16 + fr;                             \
      _Pragma("unroll") for (int kk = 0; kk < 2; ++kk)                        \
        bF[nf][kk] = *(const bf16x8*)&lds[bufc * 32768 + 16384 + R * 64 +     \
                       ((kk * 32 + fq * 8) ^ ((fr & 7) << 3))];               \
    }                                                                         \
    __builtin_amdgcn_s_setprio(1);                                            \
    _Pragma("unroll") for (int mf = 0; mf < 4; ++mf)                          \
      _Pragma("unroll") for (int nf = 0; nf < 2; ++nf)                        \
        _Pragma("unroll") for (int kk = 0; kk < 2; ++kk)                      \
          acc[(MS) * 4 + mf][(NS) * 2 + nf] =                                 \
            mfma_bf16(aF[mf][kk], bF[nf][kk], acc[(MS)*4+mf][(NS)*2+nf]);     \
    __builtin_amdgcn_s_setprio(0);                                            \
  } while (0)

__global__ __launch_bounds__(512, 1) void k_gemm8(const ushort* __restrict__ Xbc,
                                                  const ushort* __restrict__ Wxb,
                                                  const float* __restrict__ bp,
                                                  ushort* __restrict__ Axc) {
  __shared__ ushort lds[65536];   // [buf:2][op:2][256 rows][64], 128 KB

  const int tid = threadIdx.x;
  const int w = tid >> 6, l = tid & 63;
  const int wr = w >> 2, wc = w & 3;
  const int fr = l & 15, fq = l >> 4;
  const int lrow = l >> 3;                  // staging: lane's row-in-8
  const int jsw = (l & 7) ^ lrow;           // staging: swizzled col-chunk

  // bijective XCD swizzle (2048 = 8*256), n-inner for A L2-reuse
  int raw = blockIdx.x;
  int id = (raw & 7) * 256 + (raw >> 3);
  const int m0 = (id >> 4) * 256;
  const int n0 = (id & 15) * 256;

  auto stageA = [&](int buf, int H, int kt) {
    if (kt > 15) return;
    int R0a = w * 8 + H * 64;
    int R0b = 128 + w * 8 + H * 64;
    lds_load16(Xbc + (size_t)(m0 + R0a + lrow) * 1024 + kt * 64 + jsw * 8,
               &lds[buf * 32768 + R0a * 64]);
    lds_load16(Xbc + (size_t)(m0 + R0b + lrow) * 1024 + kt * 64 + jsw * 8,
               &lds[buf * 32768 + R0b * 64]);
  };
  auto stageB = [&](int buf, int H, int kt) {
    if (kt > 15) return;
    int R0a = (w >> 2) * 64 + (w & 3) * 8 + H * 32;
    int R0b = R0a + 128;
    lds_load16(Wxb + (size_t)(n0 + R0a + lrow) * 1024 + kt * 64 + jsw * 8,
               &lds[buf * 32768 + 16384 + R0a * 64]);
    lds_load16(Wxb + (size_t)(n0 + R0b + lrow) * 1024 + kt * 64 + jsw * 8,
               &lds[buf * 32768 + 16384 + R0b * 64]);
  };

  f32x4 acc[8][4] = {};

  // prologue: tile0 (all 4 halves) -> buf0, then tile1 Ah0+Bh0 -> buf1
  stageA(0, 0, 0); stageB(0, 0, 0); stageB(0, 1, 0); stageA(0, 1, 0);
  stageA(1, 0, 1); stageB(1, 0, 1);

  for (int j = 0; j < 16; ++j) {
    const int bufc = j & 1, bufn = bufc ^ 1;
    if (j < 15) { WAITV(4); } else { WAITV(0); }
    G8_PHASE(0, 0, stageB(bufn, 1, j + 1));
    G8_PHASE(0, 1, stageA(bufn, 1, j + 1));
    G8_PHASE(1, 0, stageA(bufc, 0, j + 2));
    G8_PHASE(1, 1, stageB(bufc, 0, j + 2));
  }

  // epilogue: f16 + bias
  float bias_[4];
#pragma unroll
  for (int nf = 0; nf < 4; ++nf) bias_[nf] = bp[n0 + wc * 64 + nf * 16 + fr];
#pragma unroll
  for (int mf = 0; mf < 8; ++mf) {
    int rowb = m0 + wr * 128 + mf * 16 + fq * 4;
#pragma unroll
    for (int nf = 0; nf < 4; ++nf) {
      int col = n0 + wc * 64 + nf * 16 + fr;
#pragma unroll
      for (int jr = 0; jr < 4; ++jr)
        Axc[(size_t)(rowb + jr) * NG + col] = f2h(acc[mf][nf][jr] + bias_[nf]);
    }
  }
}

// ---------------- old 128^2 GEMM (fallback for chunked path) ----------------

__global__ __launch_bounds__(256) void k_gemm1(const ushort* __restrict__ Xbc,
                                               const ushort* __restrict__ Wxb,
                                               const float* __restrict__ bp,
                                               ushort* __restrict__ Axc) {
  __shared__ ushort As[128 * 32];
  __shared__ ushort Bs[128 * 32];
  const int m0 = blockIdx.x * 128;
  const int n0 = blockIdx.y * 128;
  const int tid = threadIdx.x;
  const int w = tid >> 6, l = tid & 63;
  const int wr = w >> 1, wc = w & 1;
  const int lr = l >> 2;
  const int lc = (l & 3) * 8;
  const int fr = l & 15, fk8 = (l >> 4) * 8, fq = l >> 4;

  f32x4 acc[4][4] = {};

  for (int kb = 0; kb < 1024; kb += 32) {
    lds_load16(Xbc + (size_t)(m0 + w * 16 + lr) * 1024 + kb + lc,       &As[w * 512]);
    lds_load16(Xbc + (size_t)(m0 + (w + 4) * 16 + lr) * 1024 + kb + lc, &As[(w + 4) * 512]);
    lds_load16(Wxb + (size_t)(n0 + w * 16 + lr) * 1024 + kb + lc,       &Bs[w * 512]);
    lds_load16(Wxb + (size_t)(n0 + (w + 4) * 16 + lr) * 1024 + kb + lc, &Bs[(w + 4) * 512]);
    __syncthreads();
    bf16x8 af[4], bfr[4];
#pragma unroll
    for (int i = 0; i < 4; i++) af[i]  = *(const bf16x8*)&As[(wr * 64 + i * 16 + fr) * 32 + fk8];
#pragma unroll
    for (int i = 0; i < 4; i++) bfr[i] = *(const bf16x8*)&Bs[(wc * 64 + i * 16 + fr) * 32 + fk8];
#pragma unroll
    for (int i = 0; i < 4; i++)
#pragma unroll
      for (int jj = 0; jj < 4; jj++)
        acc[i][jj] = mfma_bf16(af[i], bfr[jj], acc[i][jj]);
    __syncthreads();
  }

#pragma unroll
  for (int jj = 0; jj < 4; jj++) {
    int gc = n0 + wc * 64 + jj * 16 + fr;
    float bb = bp[gc];
#pragma unroll
    for (int i = 0; i < 4; i++) {
      int grb = m0 + wr * 64 + i * 16 + fq * 4;
#pragma unroll
      for (int jr = 0; jr < 4; jr++)
        Axc[(size_t)(grb + jr) * NG + gc] = f2h(acc[i][jj][jr] + bb);
    }
  }
}

// ---------------- persistent recurrence chunk (r15 champion, unchanged) ----------------

__global__ __launch_bounds__(256) void k_persist(const ushort* __restrict__ Whb,
                                                 const ushort* __restrict__ Axc,
                                                 ushort* __restrict__ hb0,
                                                 ushort* __restrict__ hb1,
                                                 float* __restrict__ out,
                                                 uint32_t* __restrict__ flg2,
                                                 float* __restrict__ cst,
                                                 int t0, int TC) {
  __shared__ ushort Wlds[8192 * 8];     // 128 KB fragment-major
  __shared__ float red[4][16][65];      // K-split reduce
  __shared__ ushort h_sh[16][16];       // packed publish tile
  __shared__ float houtlds[8][256];     // 8-step out staging

  const int bid = blockIdx.x;
  const int team = bid >> 6, hg = bid & 63;
  const int tid = threadIdx.x, w = tid >> 6, l = tid & 63;
  const int fr = l & 15, fq = l >> 4;

  // ---- stage Wh slice fragment-major: f = ((kc*4)+bj)*64 + lane ----
  for (int it = 0; it < 32; ++it) {
    int f = it * 256 + tid;
    int fl = f & 63, bj = (f >> 6) & 3, kc = f >> 8;
    bf16x8 v = *(const bf16x8*)(Whb + (size_t)(hg * 64 + bj * 16 + (fl & 15)) * 1024
                                + kc * 32 + (fl >> 4) * 8);
    *(bf16x8*)&Wlds[(size_t)f * 8] = v;
  }
  __syncthreads();

  const int eb = tid >> 4, ej = tid & 15;
  const int hidx_self = (team * 16 + eb) * 1024 + hg * 16 + ej;
  float creg = cst[hidx_self];

  const size_t roff = (size_t)(team * 16 + fr) * 1024 + w * 256 + fq * 8;
  const uint32_t* fladdr = flg2 + bid * 64 + w * 16 + (l & 15);

  for (int tt = 0; tt < TC; ++tt) {
    const int t = t0 + tt;
    const ushort* hb_r = (t & 1) ? hb0 : hb1;
    ushort*       hb_w = (t & 1) ? hb1 : hb0;

    const ushort* axp = Axc + ((size_t)tt * 64 + team * 16 + eb) * NG + hg * 64;
    ushort axu0 = axp[ej], axu1 = axp[16 + ej], axu2 = axp[32 + ej], axu3 = axp[48 + ej];

    if (t > 0) {
      int guard = 0;
      while (true) {
        uint32_t v0 = ld_dword_dev(fladdr);
        uint32_t v1 = ld_dword_dev(fladdr);
        asm volatile("s_waitcnt vmcnt(1)" ::: "memory");
        __builtin_amdgcn_sched_barrier(0);
        bool ok0 = __all((int)(v0 >= (uint32_t)t));
        asm volatile("s_waitcnt vmcnt(0)" ::: "memory");
        __builtin_amdgcn_sched_barrier(0);
        if (ok0) break;
        if (__all((int)(v1 >= (uint32_t)t))) break;
        if (++guard > (1 << 15)) break;
      }
    }

    const ushort* aBt = hb_r + roff;
    u32x4 hv[8];
    f32x4 acc[4] = {};
#pragma unroll
    for (int ks = 0; ks < 8; ++ks) hv[ks] = ld_x4_dev(aBt + ks * 32);
#define SLICE(ks) do {                                                        \
      bf16x8 a_ = __builtin_bit_cast(bf16x8, hv[ks]);                         \
      _Pragma("unroll")                                                       \
      for (int bj = 0; bj < 4; ++bj) {                                        \
        bf16x8 b_ = *(const bf16x8*)&Wlds[(size_t)(((w * 8 + (ks)) * 4 + bj) * 64 + l) * 8]; \
        acc[bj] = mfma_bf16(a_, b_, acc[bj]);                                 \
      }                                                                       \
    } while (0)
    WAITV(7); SLICE(0);
    WAITV(6); SLICE(1);
    WAITV(5); SLICE(2);
    WAITV(4); SLICE(3);
    WAITV(3); SLICE(4);
    WAITV(2); SLICE(5);
    WAITV(1); SLICE(6);
    WAITV(0); SLICE(7);
#undef SLICE

#pragma unroll
    for (int bj = 0; bj < 4; ++bj)
#pragma unroll
      for (int jr = 0; jr < 4; ++jr)
        red[w][fq * 4 + jr][bj * 16 + fr] = acc[bj][jr];
    __syncthreads();

    float ai_ = h2f(axu0), af_ = h2f(axu1), ao_ = h2f(axu2), ag_ = h2f(axu3);
#pragma unroll
    for (int ww = 0; ww < 4; ++ww) {
      ai_ += red[ww][eb][ej];
      af_ += red[ww][eb][16 + ej];
      ao_ += red[ww][eb][32 + ej];
      ag_ += red[ww][eb][48 + ej];
    }

    float ig = sigm_f(ai_);
    float fg = sigm_f(af_);
    float og = sigm_f(ao_);
    float gg = tanh_f(ag_);
    creg = creg * fg + ig * gg;
    float h = og * tanh_f(creg);
    h_sh[eb][ej] = f2bf(h);
    houtlds[tt & 7][tid] = h;
    __syncthreads();

    if (w == 0) {
      if (l < 32) {
        int prow = l >> 1, phalf = (l & 1) * 8;
        u32x4 pv = *(const u32x4*)&h_sh[prow][phalf];
        st_x4_dev(hb_w + (size_t)(team * 16 + prow) * 1024 + hg * 16 + phalf, pv);
      }
      asm volatile("s_waitcnt vmcnt(0)" ::: "memory");
      __builtin_amdgcn_sched_barrier(0);
      st_dword_dev(flg2 + (team * 64 + l) * 64 + hg, (uint32_t)(t + 1));
    }

    if ((tt & 7) == 7) {
      int tb = t - 7;
#pragma unroll
      for (int s = 0; s < 8; ++s)
        out[(size_t)(tb + s) * 65536 + hidx_self] = houtlds[s][tid];
    }
    if (t == SEQ - 1) out[(size_t)SEQ * 65536 + hidx_self] = h;
  }

  cst[hidx_self] = creg;
}

// ---------------- fallback per-step kernel (ws too small for any Ax chunk) ----------------

__global__ __launch_bounds__(256) void k_step(int t,
                                              const ushort* __restrict__ Xb,
                                              const ushort* __restrict__ Wxb,
                                              const ushort* __restrict__ Whb,
                                              const float* __restrict__ bp,
                                              const ushort* __restrict__ hprev,
                                              ushort* __restrict__ hnext,
                                              float* __restrict__ cst,
                                              float* __restrict__ out) {
  __shared__ float red[4][16][65];
  const int bidx = blockIdx.x;
  const int cg = bidx & 63, mb = bidx >> 6;
  const int b0 = mb * 16, pcol = cg * 64;
  const int tid = threadIdx.x, w = tid >> 6, l = tid & 63;
  const int fr = l & 15, fk8 = (l >> 4) * 8, fq = l >> 4;

  f32x4 acc[4] = {};

  const ushort* aSrc;
  const ushort* bMat;
  int kbase;
  if (w < 2) { aSrc = Xb + (size_t)(t * 64 + b0 + fr) * 1024 + w * 512 + fk8; bMat = Wxb; kbase = w * 512; }
  else       { aSrc = hprev + (size_t)(b0 + fr) * 1024 + (w - 2) * 512 + fk8; bMat = Whb; kbase = (w - 2) * 512; }
  const ushort* bRow = bMat + (size_t)(pcol + fr) * 1024 + kbase + fk8;

#pragma unroll
  for (int ks = 0; ks < 16; ks++) {
    int kk = ks * 32;
    bf16x8 a = *(const bf16x8*)(aSrc + kk);
#pragma unroll
    for (int bj = 0; bj < 4; bj++) {
      bf16x8 bfv = *(const bf16x8*)(bRow + (size_t)bj * 16 * 1024 + kk);
      acc[bj] = mfma_bf16(a, bfv, acc[bj]);
    }
  }

#pragma unroll
  for (int bj = 0; bj < 4; bj++)
#pragma unroll
    for (int jr = 0; jr < 4; jr++)
      red[w][fq * 4 + jr][bj * 16 + fr] = acc[bj][jr];
  __syncthreads();

  const int b = tid >> 4, j = tid & 15;
  float ai_ = 0.f, af_ = 0.f, ao_ = 0.f, ag_ = 0.f;
#pragma unroll
  for (int ww = 0; ww < 4; ww++) {
    ai_ += red[ww][b][j];
    af_ += red[ww][b][16 + j];
    ao_ += red[ww][b][32 + j];
    ag_ += red[ww][b][48 + j];
  }
  ai_ += bp[pcol + j]; af_ += bp[pcol + 16 + j]; ao_ += bp[pcol + 32 + j]; ag_ += bp[pcol + 48 + j];

  float ig = sigm_f(ai_);
  float fg = sigm_f(af_);
  float og = sigm_f(ao_);
  float gg = tanh_f(ag_);
  int hidx = (b0 + b) * 1024 + cg * 16 + j;
  float cn = cst[hidx] * fg + ig * gg;
  cst[hidx] = cn;
  float h = og * tanh_f(cn);
  out[(size_t)t * 65536 + hidx] = h;
  hnext[hidx] = f2bf(h);
  if (t == SEQ - 1) out[(size_t)SEQ * 65536 + hidx] = h;
}

// ---------------- host ----------------

extern "C" void kernel_launch(void* const* d_in, const int* in_sizes, int n_in,
                              void* d_out, int out_size, void* d_ws, size_t ws_size,
                              hipStream_t stream) {
  const float* X    = (const float*)d_in[0];
  const float* W    = (const float*)d_in[1];
  const float* bvec = (const float*)d_in[2];
  float* out = (float*)d_out;
  char* ws = (char*)d_ws;

  size_t off = 0;
  auto alloc = [&](size_t bytes) -> char* {
    char* p = ws + off;
    off += (bytes + 255) & ~(size_t)255;
    return p;
  };
  ushort*   Xb   = (ushort*)alloc((size_t)SEQ * BATCH * NIN * 2);
  ushort*   Wxb  = (ushort*)alloc((size_t)NG * NIN * 2);
  ushort*   Whb  = (ushort*)alloc((size_t)NG * NHID * 2);
  float*    bp   = (float*)alloc((size_t)NG * 4);
  ushort*   hb0  = (ushort*)alloc((size_t)BATCH * NHID * 2);
  ushort*   hb1  = (ushort*)alloc((size_t)BATCH * NHID * 2);
  float*    cst  = (float*)alloc((size_t)BATCH * NHID * 4);
  uint32_t* flg2 = (uint32_t*)alloc(256 * 64 * 4);   // replicated flags
  size_t base_need = off;

  if (ws_size < base_need) return;

  // largest chunk length TC (steps) whose f16 Ax chunk fits the remaining ws
  size_t avail = ws_size - base_need;
  int TC = 0;
  for (int tc = 512; tc >= 16; tc >>= 1) {
    if ((size_t)tc * 64 * NG * 2 <= avail) { TC = tc; break; }
  }
  ushort* Axc = (ushort*)(ws + base_need);  // base_need is 256B-aligned

  k_convert_x<<<(SEQ * BATCH * NIN / 4 + 255) / 256, 256, 0, stream>>>(X, Xb, SEQ * BATCH * NIN / 4);
  k_convert_w<<<NG, 256, 0, stream>>>(W, bvec, Wxb, Whb, bp);
  k_zero<<<BATCH * NHID / 256, 256, 0, stream>>>(hb0, hb1, cst, flg2);

  if (TC == 512) {
    // single-shot: 8-phase 256^2 GEMM (M=32768, N=4096, K=1024), then persist
    k_gemm8<<<2048, 512, 0, stream>>>(Xb, Wxb, bp, Axc);
    k_persist<<<256, 256, 0, stream>>>(Whb, Axc, hb0, hb1, out, flg2, cst, 0, 512);
  } else if (TC > 0) {
    for (int c = 0; c < SEQ / TC; ++c) {
      k_gemm1<<<dim3(TC * 64 / 128, NG / 128), 256, 0, stream>>>(
          Xb + (size_t)c * TC * 64 * 1024, Wxb, bp, Axc);
      k_persist<<<256, 256, 0, stream>>>(Whb, Axc, hb0, hb1, out, flg2, cst, c * TC, TC);
    }
  } else {
    for (int t = 0; t < SEQ; t++) {
      const ushort* hp = (t & 1) ? hb1 : hb0;
      ushort*       hn = (t & 1) ? hb0 : hb1;
      k_step<<<256, 256, 0, stream>>>(t, Xb, Wxb, Whb, bp, hp, hn, cst, out);
    }
  }
}